// Round 12
// baseline (97.788 us; speedup 1.0000x reference)
//
#include <hip/hip_runtime.h>

typedef __attribute__((ext_vector_type(4))) float  f32x4;
typedef __attribute__((ext_vector_type(8))) short  bf16x8;

typedef __attribute__((address_space(3))) void lds_void_t;
typedef __attribute__((address_space(1))) void g_void_t;

#define S_LEN  2048
#define DMODEL 1024
#define NHEAD  16
#define HDIM   64
#define NBLK   128   // S/16 blocks per sequence
#define BATCH  2
#define KT     64    // keys per attn inner tile
#define VP     72    // padded row stride (shorts, multiple of 8 for b128 alignment)

__device__ __forceinline__ short f2bf(float f) {
  union { float f; unsigned u; } v; v.f = f;
  unsigned r = v.u + 0x7fffu + ((v.u >> 16) & 1u);
  return (short)(r >> 16);
}

// ---------------- merged fp32 -> bf16 convert: x + 4 weight matrices ----------------
__global__ __launch_bounds__(256) void cvt_all_kernel(
    const float* __restrict__ x,  const float* __restrict__ wq,
    const float* __restrict__ wk, const float* __restrict__ wv,
    const float* __restrict__ wo,
    short* __restrict__ xb,  short* __restrict__ wqb,
    short* __restrict__ wkb, short* __restrict__ wvb,
    short* __restrict__ wob) {
  const long i = ((long)blockIdx.x * 256 + threadIdx.x) * 8;
  const float* s; short* d; long off;
  if (i < 4194304L)      { s = x;  d = xb;  off = i; }
  else if (i < 5242880L) { s = wq; d = wqb; off = i - 4194304L; }
  else if (i < 6291456L) { s = wk; d = wkb; off = i - 5242880L; }
  else if (i < 7340032L) { s = wv; d = wvb; off = i - 6291456L; }
  else                   { s = wo; d = wob; off = i - 7340032L; }
  f32x4 a = *(const f32x4*)(s + off);
  f32x4 b = *(const f32x4*)(s + off + 4);
  bf16x8 o;
  o[0]=f2bf(a[0]); o[1]=f2bf(a[1]); o[2]=f2bf(a[2]); o[3]=f2bf(a[3]);
  o[4]=f2bf(b[0]); o[5]=f2bf(b[1]); o[6]=f2bf(b[2]); o[7]=f2bf(b[3]);
  *(bf16x8*)(d + off) = o;
}

// ---------------- QKV GEMM: 128x192 tile, BK=32, DISTANCE-3 pipeline, 2 blocks/CU ----------
// The plateau diagnosis: all distance-1 schedules (7 variants) land at ~40us because
// issue->consume (~1 tile of compute, ~500cy) < load latency (~900cy). Fix = pipeline DEPTH:
// 4 LDS buffers (A 4x8K + B 4x12K = 80 KiB exactly -> still 2 blocks/CU), stage tile t+3
// during tile t (~3 tiles ~2000cy in flight). Per tile: ONE counted wait + ONE barrier.
// Ledger (5 stage-ops/tile, per-wave in-order): end-of-tile vmcnt(10) retires stage(t+1)
// (issued 3 tiles ago), keeps t+2/t+3 (10 ops) in flight. Peel: t=NT-3 vmcnt(5), t=NT-2
// vmcnt(0), t=NT-1 none. Overwrite safety: stage(t+3) targets buf[(t-1)&3]; its readers
// (tile t-1) lgkm-drained their reads (MFMA consumption) before barrier(t-1), which
// precedes this stage issue.
// Swizzle (rule #21 both-sides, 32-col rows = 4 granules): source/read granule g^((r>>1)&3)
// (involution). Stage: thread tid -> LDS linear granule tid&3, source granule
// (tid&3)^((tid>>3)&3). Read: granule lg^((l15>>1)&3).
// XCD swizzle (T1): 512 blocks, bijective (bid&7)*64 + (bid>>3).
__global__ __launch_bounds__(256, 2) void gemm8_kernel(
    const short* __restrict__ A,
    const short* __restrict__ W0, const short* __restrict__ W1, const short* __restrict__ W2,
    const int* __restrict__ slot_map,
    short* __restrict__ qbuf, short* __restrict__ kcache, short* __restrict__ vcache)
{
  extern __shared__ short smem[];   // 40960 shorts = 80 KiB: A[4][4096] then B[4][6144]

  const int bid0 = (int)blockIdx.y * 32 + (int)blockIdx.x;   // 512 blocks
  const int bid  = (bid0 & 7) * 64 + (bid0 >> 3);            // XCD-aware, bijective
  const int m0 = (bid & 31) * 128;
  const int n0 = (bid >> 5) * 192;
  const short* Ag = A + (size_t)m0 * DMODEL;

  const int tid  = threadIdx.x;
  const int wave = tid >> 6, lane = tid & 63;
  const int l15 = lane & 15, lg = lane >> 4;
  const int wc = wave;                         // wave tile 128 x 48
  const int sgs = (tid & 3) ^ ((tid >> 3) & 3);   // stage source granule (per-thread const)
  const int rg  = (l15 >> 1) & 3;                 // read granule swizzle base

  f32x4 acc[8][3];
#pragma unroll
  for (int m = 0; m < 8; m++)
#pragma unroll
    for (int n = 0; n < 3; n++) acc[m][n] = (f32x4)0.f;

  // one stage op = 256 thr x 16B = 4KB = 64 rows x 32 cols. A: 2 ops, B: 3 ops per tile.
#define STAGE_A(BUFI, K0, P) {                                                             \
    const int r_ = (((P) * 256 + tid) >> 2);                                               \
    __builtin_amdgcn_global_load_lds(                                                      \
        (g_void_t*)(Ag + (size_t)r_ * DMODEL + (K0) + sgs * 8),                            \
        (lds_void_t*)(smem + (BUFI) * 4096 + ((P) * 256 + tid) * 8), 16, 0, 0); }

#define STAGE_B(BUFI, K0, P) {                                                             \
    const int r_ = (((P) * 256 + tid) >> 2);                                               \
    const int grow = n0 + r_;                                                              \
    const short* wb = (grow < 1024) ? W0 : (grow < 2048) ? W1 : W2;                        \
    __builtin_amdgcn_global_load_lds(                                                      \
        (g_void_t*)(wb + (size_t)(grow & 1023) * DMODEL + (K0) + sgs * 8),                 \
        (lds_void_t*)(smem + 16384 + (BUFI) * 6144 + ((P) * 256 + tid) * 8), 16, 0, 0); }

#define STAGE_TILE(BUFI, K0)                                                               \
    STAGE_A(BUFI, K0, 0); STAGE_A(BUFI, K0, 1);                                            \
    STAGE_B(BUFI, K0, 0); STAGE_B(BUFI, K0, 1); STAGE_B(BUFI, K0, 2);

  const int NT = DMODEL / 32;   // 32 K-tiles

  // ---- prologue: stage tiles 0,1,2 (15 ops); retire tile 0 (vmcnt(10)) ----
  STAGE_TILE(0, 0);
  STAGE_TILE(1, 32);
  STAGE_TILE(2, 64);
  asm volatile("s_waitcnt vmcnt(10)" ::: "memory");
  __builtin_amdgcn_s_barrier();
  asm volatile("" ::: "memory");

  for (int t = 0; t < NT; ++t) {
    const int bi = t & 3;
    if (t + 3 < NT) {
      const int bn = (t + 3) & 3;
      const int kn = (t + 3) * 32;
      STAGE_TILE(bn, kn);
    }
    const short* Ac = smem + bi * 4096;
    const short* Bc = smem + 16384 + bi * 6144;

    bf16x8 af[8], bfr[3];
#pragma unroll
    for (int nt = 0; nt < 3; ++nt) {
      const int row = wc * 48 + nt * 16 + l15;
      bfr[nt] = *(const bf16x8*)(Bc + row * 32 + ((lg ^ rg) << 3));
    }
#pragma unroll
    for (int mi = 0; mi < 8; ++mi) {
      const int row = mi * 16 + l15;
      af[mi] = *(const bf16x8*)(Ac + row * 32 + ((lg ^ rg) << 3));
    }
    __builtin_amdgcn_s_setprio(1);
#pragma unroll
    for (int mi = 0; mi < 8; ++mi)
#pragma unroll
      for (int nt = 0; nt < 3; ++nt)
        acc[mi][nt] = __builtin_amdgcn_mfma_f32_16x16x32_bf16(
            af[mi], bfr[nt], acc[mi][nt], 0, 0, 0);
    __builtin_amdgcn_s_setprio(0);

    // counted wait: retire stage(t+1) (issued 3 tiles ago); keep deeper stages in flight
    if (t < NT - 3)       { asm volatile("s_waitcnt vmcnt(10)" ::: "memory"); }
    else if (t == NT - 3) { asm volatile("s_waitcnt vmcnt(5)"  ::: "memory"); }
    else if (t == NT - 2) { asm volatile("s_waitcnt vmcnt(0)"  ::: "memory"); }
    if (t < NT - 1) {
      asm volatile("" ::: "memory");
      __builtin_amdgcn_s_barrier();
      asm volatile("" ::: "memory");
    }
  }
#undef STAGE_A
#undef STAGE_B
#undef STAGE_TILE

  // ---- epilogue: scatter to q / k / v ----
#pragma unroll
  for (int mf = 0; mf < 8; ++mf) {
    const int rowb = m0 + mf * 16 + lg * 4;
#pragma unroll
    for (int r4 = 0; r4 < 4; ++r4) {
      const int row = rowb + r4;
      const int slot = slot_map[row];
#pragma unroll
      for (int nt = 0; nt < 3; ++nt) {
        const int col = n0 + wc * 48 + nt * 16 + l15;
        const short bv = f2bf(acc[mf][nt][r4]);
        if (col < DMODEL)
          qbuf[(size_t)row * DMODEL + col] = bv;
        else if (col < 2 * DMODEL)
          kcache[(size_t)slot * DMODEL + (col - DMODEL)] = bv;
        else
          vcache[(size_t)slot * DMODEL + (col - 2 * DMODEL)] = bv;
      }
    }
  }
}

// ---------------- out-proj GEMM: 128x128 tile, BK=64, 4 waves (2x2), counted-vmcnt dbuf ----
// XCD swizzle (T1): 256 blocks, bijective (bid&7)*32 + (bid>>3).
__global__ __launch_bounds__(256, 2) void gemm1_kernel(
    const short* __restrict__ A, const short* __restrict__ W,
    float* __restrict__ outf)
{
  extern __shared__ short smem1[];   // 32768 shorts = 64 KiB

  const int bid0 = (int)blockIdx.y * 32 + (int)blockIdx.x;   // 256 blocks
  const int bid  = (bid0 & 7) * 32 + (bid0 >> 3);            // XCD-aware, bijective
  const int m0 = (bid & 31) * 128;
  const int n0 = (bid >> 5) * 128;
  const short* Ag = A + (size_t)m0 * DMODEL;
  const short* Bg = W + (size_t)n0 * DMODEL;

  const int tid = threadIdx.x;
  const int wave = tid >> 6, lane = tid & 63;
  const int l15 = lane & 15, lg = lane >> 4;
  const int wr = wave >> 1, wc = wave & 1;   // wave tile 64 x 64
  const int swz = l15 & 7;

  short* const As0 = smem1;           // [128][64]
  short* const Bs0 = smem1 + 8192;
  short* const As1 = smem1 + 16384;
  short* const Bs1 = smem1 + 24576;

  f32x4 acc[4][4];
#pragma unroll
  for (int m = 0; m < 4; m++)
#pragma unroll
    for (int n = 0; n < 4; n++) acc[m][n] = (f32x4)0.f;

#define STG1(LA, LB, K0) {                                                                 \
    _Pragma("unroll") for (int p = 0; p < 4; ++p) {                                        \
      const int u = p * 256 + tid; const int r = u >> 3; const int cs = (u & 7) ^ (r & 7); \
      __builtin_amdgcn_global_load_lds((g_void_t*)(Ag + (size_t)r * DMODEL + (K0) + cs * 8), \
          (lds_void_t*)((LA) + (p * 256 + wave * 64) * 8), 16, 0, 0); }                    \
    _Pragma("unroll") for (int p = 0; p < 4; ++p) {                                        \
      const int u = p * 256 + tid; const int r = u >> 3; const int cs = (u & 7) ^ (r & 7); \
      __builtin_amdgcn_global_load_lds((g_void_t*)(Bg + (size_t)r * DMODEL + (K0) + cs * 8), \
          (lds_void_t*)((LB) + (p * 256 + wave * 64) * 8), 16, 0, 0); } }

  STG1(As0, Bs0, 0);
  asm volatile("s_waitcnt vmcnt(0)" ::: "memory");
  __builtin_amdgcn_s_barrier();
  asm volatile("" ::: "memory");

  for (int t = 0; t < 16; ++t) {
    const int cur = t & 1;
    short* const Ac = cur ? As1 : As0;
    short* const Bc = cur ? Bs1 : Bs0;
    short* const An = cur ? As0 : As1;
    short* const Bn = cur ? Bs0 : Bs1;
    if (t + 1 < 16) {
      STG1(An, Bn, (t + 1) * 64);
      asm volatile("s_waitcnt vmcnt(8)" ::: "memory");   // tile t retired; t+1's 8 in flight
    } else {
      asm volatile("s_waitcnt vmcnt(0)" ::: "memory");
    }
    asm volatile("" ::: "memory");
    __builtin_amdgcn_s_barrier();
    asm volatile("" ::: "memory");

    bf16x8 af[4][2], bfr[4][2];
#pragma unroll
    for (int m4 = 0; m4 < 4; ++m4) {
      const int row = wr * 64 + m4 * 16 + l15;
#pragma unroll
      for (int ks = 0; ks < 2; ++ks)
        af[m4][ks] = *(const bf16x8*)(Ac + row * 64 + (((ks * 4 + lg) ^ swz) << 3));
    }
#pragma unroll
    for (int n4 = 0; n4 < 4; ++n4) {
      const int row = wc * 64 + n4 * 16 + l15;
#pragma unroll
      for (int ks = 0; ks < 2; ++ks)
        bfr[n4][ks] = *(const bf16x8*)(Bc + row * 64 + (((ks * 4 + lg) ^ swz) << 3));
    }
    __builtin_amdgcn_s_setprio(1);
#pragma unroll
    for (int m4 = 0; m4 < 4; ++m4)
#pragma unroll
      for (int n4 = 0; n4 < 4; ++n4)
#pragma unroll
        for (int ks = 0; ks < 2; ++ks)
          acc[m4][n4] = __builtin_amdgcn_mfma_f32_16x16x32_bf16(af[m4][ks], bfr[n4][ks], acc[m4][n4], 0, 0, 0);
    __builtin_amdgcn_s_setprio(0);

    asm volatile("" ::: "memory");
    __builtin_amdgcn_s_barrier();
    asm volatile("" ::: "memory");
  }
#undef STG1

#pragma unroll
  for (int m4 = 0; m4 < 4; ++m4) {
    const int rowb = m0 + wr * 64 + m4 * 16 + lg * 4;
#pragma unroll
    for (int n4 = 0; n4 < 4; ++n4) {
      const int col = n0 + wc * 64 + n4 * 16 + l15;
#pragma unroll
      for (int r4 = 0; r4 < 4; ++r4)
        outf[(size_t)(rowb + r4) * DMODEL + col] = acc[m4][n4][r4];
    }
  }
}

// ---------------- sliding-window flash attention (proven config: single-buffer, 4/CU) ----
// grid: (S/128, H, B), block 512 (8 waves), wave owns 16 q-rows.
// Fixed-shift softmax (p = exp(s - 12)); register-prefetched K/V staging one tile ahead.
// Balance flip: bz==1 reverses bx so co-resident blocks pair light+heavy q-tiles.
__global__ __launch_bounds__(512, 4) void attn_kernel(
    const short* __restrict__ qbuf,
    const short* __restrict__ kcache, const short* __restrict__ vcache,
    const int* __restrict__ block_tables, const int* __restrict__ context_lens,
    const int* __restrict__ window_size,
    short* __restrict__ attn_out)
{
  __shared__ short Ks[KT * 64];        // XOR-swizzled rows (row stride 128B)
  __shared__ short Vt[HDIM * VP];      // V^T, key-rotated within rows, stride 72
  __shared__ short Pb[8 * 16 * VP];    // per-wave P tiles, stride 72

  const int b = blockIdx.z, h = blockIdx.y;
  const int bx = (b & 1) ? ((int)gridDim.x - 1 - (int)blockIdx.x) : (int)blockIdx.x;
  const int q0 = bx * 128;
  const int ctx = context_lens[b];
  const int ws  = window_size[0];
  const int* bt = block_tables + b * NBLK;

  const int tid  = threadIdx.x;
  const int wave = tid >> 6, lane = tid & 63;
  const int l15 = lane & 15, lg = lane >> 4;
  const int qw = q0 + wave * 16;       // this wave's 16 q-rows

  const short* qp = qbuf + ((size_t)(b * S_LEN + qw + l15)) * DMODEL + h * HDIM;
  const bf16x8 qf0 = *(const bf16x8*)(qp + lg * 8);
  const bf16x8 qf1 = *(const bf16x8*)(qp + 32 + lg * 8);

  f32x4 oacc[4];
  float lrow[4];
#pragma unroll
  for (int i = 0; i < 4; i++) { oacc[i] = (f32x4)0.f; lrow[i] = 0.f; }

  int kstart = q0 - ws + 1; if (kstart < 0) kstart = 0; kstart &= ~(KT - 1);
  int kend = q0 + 128; if (kend > ctx) kend = ctx;

  const int kr = tid >> 3;             // staging: tile-local key 0..63
  const int dc = (tid & 7) << 3;       // staging: d-chunk
  const float rscale = 0.125f;         // HD^-0.5
  const float FM = 12.f;               // fixed softmax shift
  short* pw = Pb + wave * (16 * VP);
  const int swz = (l15 & 7) << 4;

  bf16x8 kreg = (bf16x8)0, vreg = (bf16x8)0;
  {
    const int key = kstart + kr;
    if (key < ctx) {
      const int slot = bt[key >> 4] * 16 + (key & 15);
      kreg = *(const bf16x8*)(kcache + (size_t)slot * DMODEL + h * HDIM + dc);
      vreg = *(const bf16x8*)(vcache + (size_t)slot * DMODEL + h * HDIM + dc);
    }
  }

  for (int kt = kstart; kt < kend; kt += KT) {
    __syncthreads();
    *(bf16x8*)((char*)Ks + kr * 128 + ((dc * 2) ^ ((kr & 7) << 4))) = kreg;
    const int vcol = (kr + dc) & 63;
#pragma unroll
    for (int j = 0; j < 8; j++) Vt[(dc + j) * VP + vcol] = vreg[j];
    kreg = (bf16x8)0; vreg = (bf16x8)0;
    if (kt + KT < kend) {
      const int key = kt + KT + kr;
      if (key < ctx) {
        const int slot = bt[key >> 4] * 16 + (key & 15);
        kreg = *(const bf16x8*)(kcache + (size_t)slot * DMODEL + h * HDIM + dc);
        vreg = *(const bf16x8*)(vcache + (size_t)slot * DMODEL + h * HDIM + dc);
      }
    }
    __syncthreads();

    if ((kt > qw + 15) || (kt + (KT - 1) <= qw - ws)) continue;

    f32x4 sacc[4];
#pragma unroll
    for (int cg = 0; cg < 4; cg++) sacc[cg] = (f32x4)0.f;
#pragma unroll
    for (int cg = 0; cg < 4; cg++) {
      const char* kp = (const char*)Ks + (cg * 16 + l15) * 128;
      const bf16x8 k0 = *(const bf16x8*)(kp + ((lg * 16) ^ swz));
      const bf16x8 k1 = *(const bf16x8*)(kp + ((64 + lg * 16) ^ swz));
      sacc[cg] = __builtin_amdgcn_mfma_f32_16x16x32_bf16(qf0, k0, sacc[cg], 0, 0, 0);
      sacc[cg] = __builtin_amdgcn_mfma_f32_16x16x32_bf16(qf1, k1, sacc[cg], 0, 0, 0);
    }

    const bool fullvis = (kt + (KT - 1) <= qw) && (qw + 15 - kt < ws) && (kt + (KT - 1) < ctx);

    if (fullvis) {
#pragma unroll
      for (int r = 0; r < 4; r++) {
        const float e0 = __expf(sacc[0][r] * rscale - FM);
        const float e1 = __expf(sacc[1][r] * rscale - FM);
        const float e2 = __expf(sacc[2][r] * rscale - FM);
        const float e3 = __expf(sacc[3][r] * rscale - FM);
        lrow[r] += (e0 + e1) + (e2 + e3);
        short* pr = pw + (lg * 4 + r) * VP + l15;
        pr[0]  = f2bf(e0); pr[16] = f2bf(e1);
        pr[32] = f2bf(e2); pr[48] = f2bf(e3);
      }
    } else {
#pragma unroll
      for (int r = 0; r < 4; r++) {
        const int qrow = qw + lg * 4 + r;
        const int key0 = kt + l15;
        const bool ok0 = (key0      <= qrow) && (qrow - key0      < ws) && (key0      < ctx);
        const bool ok1 = (key0 + 16 <= qrow) && (qrow - key0 - 16 < ws) && (key0 + 16 < ctx);
        const bool ok2 = (key0 + 32 <= qrow) && (qrow - key0 - 32 < ws) && (key0 + 32 < ctx);
        const bool ok3 = (key0 + 48 <= qrow) && (qrow - key0 - 48 < ws) && (key0 + 48 < ctx);
        const float e0 = ok0 ? __expf(sacc[0][r] * rscale - FM) : 0.f;
        const float e1 = ok1 ? __expf(sacc[1][r] * rscale - FM) : 0.f;
        const float e2 = ok2 ? __expf(sacc[2][r] * rscale - FM) : 0.f;
        const float e3 = ok3 ? __expf(sacc[3][r] * rscale - FM) : 0.f;
        lrow[r] += (e0 + e1) + (e2 + e3);
        short* pr = pw + (lg * 4 + r) * VP + l15;
        pr[0]  = f2bf(e0); pr[16] = f2bf(e1);
        pr[32] = f2bf(e2); pr[48] = f2bf(e3);
      }
    }

    asm volatile("s_waitcnt lgkmcnt(0)" ::: "memory");

#pragma unroll
    for (int kk = 0; kk < 2; kk++) {
      const bf16x8 pa = *(const bf16x8*)(pw + l15 * VP + kk * 32 + lg * 8);
#pragma unroll
      for (int dn = 0; dn < 4; dn++) {
        const int vrow = dn * 16 + l15;
        const int roff = (kk * 32 + lg * 8 + (vrow & ~7)) & 63;
        const bf16x8 vb = *(const bf16x8*)(Vt + vrow * VP + roff);
        oacc[dn] = __builtin_amdgcn_mfma_f32_16x16x32_bf16(pa, vb, oacc[dn], 0, 0, 0);
      }
    }
  }

#pragma unroll
  for (int r = 0; r < 4; r++) {
    float ls = lrow[r];
    ls += __shfl_xor(ls, 1); ls += __shfl_xor(ls, 2);
    ls += __shfl_xor(ls, 4); ls += __shfl_xor(ls, 8);
    const float inv = 1.f / fmaxf(ls, 1e-30f);
    const int row = qw + lg * 4 + r;
    short* op = attn_out + ((size_t)(b * S_LEN + row)) * DMODEL + h * HDIM;
#pragma unroll
    for (int dn = 0; dn < 4; dn++)
      op[dn * 16 + l15] = f2bf(oacc[dn][r] * inv);
  }
}

// ---------------- launch ----------------
extern "C" void kernel_launch(void* const* d_in, const int* in_sizes, int n_in,
                              void* d_out, int out_size, void* d_ws, size_t ws_size,
                              hipStream_t stream) {
  const float* x  = (const float*)d_in[0];
  const float* wq = (const float*)d_in[1];
  const float* wk = (const float*)d_in[2];
  const float* wv = (const float*)d_in[3];
  const float* wo = (const float*)d_in[4];
  const int* block_tables = (const int*)d_in[5];
  const int* slot_mapping = (const int*)d_in[6];
  const int* context_lens = (const int*)d_in[7];
  const int* window_size  = (const int*)d_in[8];
  float* out = (float*)d_out;

  char* ws = (char*)d_ws;
  short* xb     = (short*)(ws + (size_t)( 0 << 20));
  short* wqb    = (short*)(ws + (size_t)( 8 << 20));
  short* wkb    = (short*)(ws + (size_t)(10 << 20));
  short* wvb    = (short*)(ws + (size_t)(12 << 20));
  short* wob    = (short*)(ws + (size_t)(14 << 20));
  short* qbuf   = (short*)(ws + (size_t)(16 << 20));
  short* kcache = (short*)(ws + (size_t)(24 << 20));
  short* vcache = (short*)(ws + (size_t)(32 << 20));
  short* abuf   = (short*)(ws + (size_t)(40 << 20));

  // one-time: allow dynamic LDS (host state calls, not stream-captured)
  static bool ginit = [] {
    hipFuncSetAttribute(reinterpret_cast<const void*>(&gemm8_kernel),
                        hipFuncAttributeMaxDynamicSharedMemorySize, 81920);
    hipFuncSetAttribute(reinterpret_cast<const void*>(&gemm1_kernel),
                        hipFuncAttributeMaxDynamicSharedMemorySize, 65536);
    return true;
  }();
  (void)ginit;

  cvt_all_kernel<<<4096, 256, 0, stream>>>(x, wq, wk, wv, wo, xb, wqb, wkb, wvb, wob);

  gemm8_kernel<<<dim3(32, 16), 256, 81920, stream>>>(xb, wqb, wkb, wvb, slot_mapping,
                                                     qbuf, kcache, vcache);

  attn_kernel<<<dim3(S_LEN / 128, NHEAD, BATCH), 512, 0, stream>>>(
      qbuf, kcache, vcache, block_tables, context_lens, window_size, abuf);

  gemm1_kernel<<<dim3(32, 8), 256, 65536, stream>>>(abuf, wob, out);
}

// Round 13
// 89.744 us; speedup vs baseline: 1.0896x; 1.0896x over previous
//
#include <hip/hip_runtime.h>

typedef __attribute__((ext_vector_type(4))) float  f32x4;
typedef __attribute__((ext_vector_type(8))) short  bf16x8;

typedef __attribute__((address_space(3))) void lds_void_t;
typedef __attribute__((address_space(1))) void g_void_t;

#define S_LEN  2048
#define DMODEL 1024
#define NHEAD  16
#define HDIM   64
#define NBLK   128   // S/16 blocks per sequence
#define BATCH  2
#define KT     64    // keys per attn inner tile
#define VP     72    // padded row stride (shorts, multiple of 8 for b128 alignment)

__device__ __forceinline__ short f2bf(float f) {
  union { float f; unsigned u; } v; v.f = f;
  unsigned r = v.u + 0x7fffu + ((v.u >> 16) & 1u);
  return (short)(r >> 16);
}

// ---------------- merged fp32 -> bf16 convert: x + 4 weight matrices ----------------
__global__ __launch_bounds__(256) void cvt_all_kernel(
    const float* __restrict__ x,  const float* __restrict__ wq,
    const float* __restrict__ wk, const float* __restrict__ wv,
    const float* __restrict__ wo,
    short* __restrict__ xb,  short* __restrict__ wqb,
    short* __restrict__ wkb, short* __restrict__ wvb,
    short* __restrict__ wob) {
  const long i = ((long)blockIdx.x * 256 + threadIdx.x) * 8;
  const float* s; short* d; long off;
  if (i < 4194304L)      { s = x;  d = xb;  off = i; }
  else if (i < 5242880L) { s = wq; d = wqb; off = i - 4194304L; }
  else if (i < 6291456L) { s = wk; d = wkb; off = i - 5242880L; }
  else if (i < 7340032L) { s = wv; d = wvb; off = i - 6291456L; }
  else                   { s = wo; d = wob; off = i - 7340032L; }
  f32x4 a = *(const f32x4*)(s + off);
  f32x4 b = *(const f32x4*)(s + off + 4);
  bf16x8 o;
  o[0]=f2bf(a[0]); o[1]=f2bf(a[1]); o[2]=f2bf(a[2]); o[3]=f2bf(a[3]);
  o[4]=f2bf(b[0]); o[5]=f2bf(b[1]); o[6]=f2bf(b[2]); o[7]=f2bf(b[3]);
  *(bf16x8*)(d + off) = o;
}

// ---------------- QKV GEMM: faithful m201 8-phase port ----------------
// 256x256 tile, BK=64, 8 waves (2M x 4N, wave tile 128x64), LDS 128 KiB (A/B x dbuf).
// 2 K-tiles per iteration, 8 phases; each phase: {ds_read subtile | 2x global_load_lds ->
// barrier -> lgkmcnt(0) -> setprio(1) -> 16 MFMA -> setprio(0) -> barrier}.
// Counted vmcnt(2) ONLY at phases 4 and 8 (retires the 8 oldest ops = one K-tile's staging,
// issued 4-7 phases earlier); drains to 0 only on the final K-tile.
// Stage plan (2 ops/phase; op = 512thr x 16B = 64 rows):
//   P1: A1 p2,p3 (T1=K0+64)   P2: B1 p0,p1   P3: B1 p2,p3      <- T1, read P5-P7
//   P4: A0 p0,p1 (T0'=K0+128) P5: A0 p2,p3   P6: B0 p0,p1  P7: B0 p2,p3  <- next iter
//   P8: A1 p0,p1 (T1'=K0+192)                                  <- next iter's T1 head
// Overwrite safety: each stage targets a buffer whose last ds_reads were lgkm-completed
// before a barrier preceding the stage issue (A1/B1 read P5-P7 prev iter -> staged P8/P1-P3;
// A0/B0 read P1-P3 -> staged P4-P7).
// Swizzle (rule #21 both-sides): global granule col (g&7)^(r&7), ds_read applies same XOR.
// XCD swizzle (T1): 192 blocks, 192%8==0 -> bijective (b&7)*24 + (b>>3).
__global__ __launch_bounds__(512, 2) void gemm8_kernel(
    const short* __restrict__ A,
    const short* __restrict__ W0, const short* __restrict__ W1, const short* __restrict__ W2,
    const int* __restrict__ slot_map,
    short* __restrict__ qbuf, short* __restrict__ kcache, short* __restrict__ vcache)
{
  extern __shared__ short smem[];   // 65536 shorts = 128 KiB

  const int bid0 = (int)blockIdx.y * 16 + (int)blockIdx.x;   // 192 blocks
  const int bid  = (bid0 & 7) * 24 + (bid0 >> 3);            // XCD-aware, bijective
  const int m0 = (bid & 15) * 256;
  const int n0 = (bid >> 4) * 256;
  const int wsel = n0 >> 10;        // uniform per block (256 | 1024)
  const short* W = (wsel == 0) ? W0 : (wsel == 1) ? W1 : W2;
  const short* Ag = A + (size_t)m0 * DMODEL;
  const short* Bg = W + (size_t)(n0 & 1023) * DMODEL;

  const int tid  = threadIdx.x;
  const int wave = tid >> 6, lane = tid & 63;
  const int l15 = lane & 15, lg = lane >> 4;
  const int wr = wave >> 2, wc = wave & 3;   // wave tile 128 x 64
  const int swz = l15 & 7;

  short* const A0s = smem;            // [256][64]
  short* const A1s = smem + 16384;
  short* const B0s = smem + 32768;
  short* const B1s = smem + 49152;

  f32x4 acc[8][4];
#pragma unroll
  for (int m = 0; m < 8; m++)
#pragma unroll
    for (int n = 0; n < 4; n++) acc[m][n] = (f32x4)0.f;

#define STG_A(DST, K0, P) {                                                                \
    const int g_ = (P) * 512 + tid;                                                        \
    const int r_ = g_ >> 3;                                                                \
    const int cs_ = (g_ & 7) ^ (r_ & 7);                                                   \
    __builtin_amdgcn_global_load_lds((g_void_t*)(Ag + (size_t)r_ * DMODEL + (K0) + cs_ * 8), \
        (lds_void_t*)((DST) + ((P) * 512 + wave * 64) * 8), 16, 0, 0); }

#define STG_B(DST, K0, P) {                                                                \
    const int g_ = (P) * 512 + tid;                                                        \
    const int r_ = g_ >> 3;                                                                \
    const int cs_ = (g_ & 7) ^ (r_ & 7);                                                   \
    __builtin_amdgcn_global_load_lds((g_void_t*)(Bg + (size_t)r_ * DMODEL + (K0) + cs_ * 8), \
        (lds_void_t*)((DST) + ((P) * 512 + wave * 64) * 8), 16, 0, 0); }

#define BAR() do { asm volatile("" ::: "memory");                \
    __builtin_amdgcn_s_barrier();                                \
    asm volatile("" ::: "memory"); } while (0)

#define LGKM0() asm volatile("s_waitcnt lgkmcnt(0)" ::: "memory")

#define RD_A(DEST, BUF, MH)                                                                \
    _Pragma("unroll") for (int mi = 0; mi < 4; ++mi) {                                     \
      const int row = wr * 128 + (MH) * 64 + mi * 16 + l15;                                \
      _Pragma("unroll") for (int ks = 0; ks < 2; ++ks)                                     \
        DEST[mi][ks] = *(const bf16x8*)((BUF) + row * 64 + (((ks * 4 + lg) ^ swz) << 3)); }

#define RD_B(DEST, BUF, NH)                                                                \
    _Pragma("unroll") for (int ni = 0; ni < 2; ++ni) {                                     \
      const int row = wc * 64 + (NH) * 32 + ni * 16 + l15;                                 \
      _Pragma("unroll") for (int ks = 0; ks < 2; ++ks)                                     \
        DEST[ni][ks] = *(const bf16x8*)((BUF) + row * 64 + (((ks * 4 + lg) ^ swz) << 3)); }

#define MMA(MH, NH, AF, BF)                                                                \
    __builtin_amdgcn_s_setprio(1);                                                         \
    _Pragma("unroll") for (int mi = 0; mi < 4; ++mi)                                       \
    _Pragma("unroll") for (int ni = 0; ni < 2; ++ni)                                       \
    _Pragma("unroll") for (int ks = 0; ks < 2; ++ks)                                       \
      acc[(MH) * 4 + mi][(NH) * 2 + ni] = __builtin_amdgcn_mfma_f32_16x16x32_bf16(         \
          AF[mi][ks], BF[ni][ks], acc[(MH) * 4 + mi][(NH) * 2 + ni], 0, 0, 0);             \
    __builtin_amdgcn_s_setprio(0);

  // ---- prologue: T0 (8 ops) + T1 head (A1 p0,p1); retire T0, keep 2 in flight ----
  STG_A(A0s, 0, 0); STG_A(A0s, 0, 1); STG_A(A0s, 0, 2); STG_A(A0s, 0, 3);
  STG_B(B0s, 0, 0); STG_B(B0s, 0, 1); STG_B(B0s, 0, 2); STG_B(B0s, 0, 3);
  STG_A(A1s, 64, 0); STG_A(A1s, 64, 1);
  asm volatile("s_waitcnt vmcnt(2)" ::: "memory");
  BAR();

  const int NI = DMODEL / 128;   // 8 iterations x 2 K-tiles
  for (int i = 0; i < NI; ++i) {
    const int K0 = i * 128;
    const bool lst = (i == NI - 1);
    bf16x8 af0[4][2], af1[4][2], bf0[2][2], bf1[2][2];

    // ---- P1: rd A0.mh0 (8) + B0.nh0 (4); stage A1 p2,p3 (T1) ----
    RD_A(af0, A0s, 0); RD_B(bf0, B0s, 0);
    STG_A(A1s, K0 + 64, 2); STG_A(A1s, K0 + 64, 3);
    BAR(); LGKM0();
    MMA(0, 0, af0, bf0);
    BAR();

    // ---- P2: rd B0.nh1 (4); stage B1 p0,p1 ----
    RD_B(bf1, B0s, 1);
    STG_B(B1s, K0 + 64, 0); STG_B(B1s, K0 + 64, 1);
    BAR(); LGKM0();
    MMA(0, 1, af0, bf1);
    BAR();

    // ---- P3: rd A0.mh1 (8); stage B1 p2,p3 ----
    RD_A(af1, A0s, 1);
    STG_B(B1s, K0 + 64, 2); STG_B(B1s, K0 + 64, 3);
    BAR(); LGKM0();
    MMA(1, 0, af1, bf0);
    BAR();

    // ---- P4: reg-only MFMA; stage A0 p0,p1 (T0'); vmcnt retires T1's 8 ops ----
    if (!lst) { STG_A(A0s, K0 + 128, 0); STG_A(A0s, K0 + 128, 1); }
    MMA(1, 1, af1, bf1);
    if (!lst) { asm volatile("s_waitcnt vmcnt(2)" ::: "memory"); }
    else      { asm volatile("s_waitcnt vmcnt(0)" ::: "memory"); }
    BAR();

    // ---- P5: rd A1.mh0 + B1.nh0; stage A0 p2,p3 ----
    RD_A(af0, A1s, 0); RD_B(bf0, B1s, 0);
    if (!lst) { STG_A(A0s, K0 + 128, 2); STG_A(A0s, K0 + 128, 3); }
    BAR(); LGKM0();
    MMA(0, 0, af0, bf0);
    BAR();

    // ---- P6: rd B1.nh1; stage B0 p0,p1 ----
    RD_B(bf1, B1s, 1);
    if (!lst) { STG_B(B0s, K0 + 128, 0); STG_B(B0s, K0 + 128, 1); }
    BAR(); LGKM0();
    MMA(0, 1, af0, bf1);
    BAR();

    // ---- P7: rd A1.mh1; stage B0 p2,p3 ----
    RD_A(af1, A1s, 1);
    if (!lst) { STG_B(B0s, K0 + 128, 2); STG_B(B0s, K0 + 128, 3); }
    BAR(); LGKM0();
    MMA(1, 0, af1, bf0);
    BAR();

    // ---- P8: reg-only MFMA; stage A1 p0,p1 (T1'); vmcnt retires T0''s 8 ops ----
    if (!lst) { STG_A(A1s, K0 + 192, 0); STG_A(A1s, K0 + 192, 1); }
    MMA(1, 1, af1, bf1);
    if (!lst) {
      asm volatile("s_waitcnt vmcnt(2)" ::: "memory");
      BAR();
    }
  }
#undef STG_A
#undef STG_B
#undef BAR
#undef LGKM0
#undef RD_A
#undef RD_B
#undef MMA

  // ---- epilogue: scatter to q / k / v (wsel uniform per block) ----
  const int colb = (n0 & 1023) + wc * 64;
#pragma unroll
  for (int mf = 0; mf < 8; ++mf) {
    const int rowb = m0 + wr * 128 + mf * 16 + lg * 4;
#pragma unroll
    for (int r4 = 0; r4 < 4; ++r4) {
      const int row = rowb + r4;
      short* base;
      if (wsel == 0) base = qbuf + (size_t)row * DMODEL;
      else {
        const int slot = slot_map[row];
        base = ((wsel == 1) ? kcache : vcache) + (size_t)slot * DMODEL;
      }
#pragma unroll
      for (int nf = 0; nf < 4; ++nf)
        base[colb + nf * 16 + l15] = f2bf(acc[mf][nf][r4]);
    }
  }
}

// ---------------- out-proj GEMM: 128x128 tile, BK=64, 4 waves (2x2), counted-vmcnt dbuf ----
// XCD swizzle (T1): 256 blocks, bijective (bid&7)*32 + (bid>>3).
__global__ __launch_bounds__(256, 2) void gemm1_kernel(
    const short* __restrict__ A, const short* __restrict__ W,
    float* __restrict__ outf)
{
  extern __shared__ short smem1[];   // 32768 shorts = 64 KiB

  const int bid0 = (int)blockIdx.y * 32 + (int)blockIdx.x;   // 256 blocks
  const int bid  = (bid0 & 7) * 32 + (bid0 >> 3);            // XCD-aware, bijective
  const int m0 = (bid & 31) * 128;
  const int n0 = (bid >> 5) * 128;
  const short* Ag = A + (size_t)m0 * DMODEL;
  const short* Bg = W + (size_t)n0 * DMODEL;

  const int tid = threadIdx.x;
  const int wave = tid >> 6, lane = tid & 63;
  const int l15 = lane & 15, lg = lane >> 4;
  const int wr = wave >> 1, wc = wave & 1;   // wave tile 64 x 64
  const int swz = l15 & 7;

  short* const As0 = smem1;           // [128][64]
  short* const Bs0 = smem1 + 8192;
  short* const As1 = smem1 + 16384;
  short* const Bs1 = smem1 + 24576;

  f32x4 acc[4][4];
#pragma unroll
  for (int m = 0; m < 4; m++)
#pragma unroll
    for (int n = 0; n < 4; n++) acc[m][n] = (f32x4)0.f;

#define STG1(LA, LB, K0) {                                                                 \
    _Pragma("unroll") for (int p = 0; p < 4; ++p) {                                        \
      const int u = p * 256 + tid; const int r = u >> 3; const int cs = (u & 7) ^ (r & 7); \
      __builtin_amdgcn_global_load_lds((g_void_t*)(Ag + (size_t)r * DMODEL + (K0) + cs * 8), \
          (lds_void_t*)((LA) + (p * 256 + wave * 64) * 8), 16, 0, 0); }                    \
    _Pragma("unroll") for (int p = 0; p < 4; ++p) {                                        \
      const int u = p * 256 + tid; const int r = u >> 3; const int cs = (u & 7) ^ (r & 7); \
      __builtin_amdgcn_global_load_lds((g_void_t*)(Bg + (size_t)r * DMODEL + (K0) + cs * 8), \
          (lds_void_t*)((LB) + (p * 256 + wave * 64) * 8), 16, 0, 0); } }

  STG1(As0, Bs0, 0);
  asm volatile("s_waitcnt vmcnt(0)" ::: "memory");
  __builtin_amdgcn_s_barrier();
  asm volatile("" ::: "memory");

  for (int t = 0; t < 16; ++t) {
    const int cur = t & 1;
    short* const Ac = cur ? As1 : As0;
    short* const Bc = cur ? Bs1 : Bs0;
    short* const An = cur ? As0 : As1;
    short* const Bn = cur ? Bs0 : Bs1;
    if (t + 1 < 16) {
      STG1(An, Bn, (t + 1) * 64);
      asm volatile("s_waitcnt vmcnt(8)" ::: "memory");   // tile t retired; t+1's 8 in flight
    } else {
      asm volatile("s_waitcnt vmcnt(0)" ::: "memory");
    }
    asm volatile("" ::: "memory");
    __builtin_amdgcn_s_barrier();
    asm volatile("" ::: "memory");

    bf16x8 af[4][2], bfr[4][2];
#pragma unroll
    for (int m4 = 0; m4 < 4; ++m4) {
      const int row = wr * 64 + m4 * 16 + l15;
#pragma unroll
      for (int ks = 0; ks < 2; ++ks)
        af[m4][ks] = *(const bf16x8*)(Ac + row * 64 + (((ks * 4 + lg) ^ swz) << 3));
    }
#pragma unroll
    for (int n4 = 0; n4 < 4; ++n4) {
      const int row = wc * 64 + n4 * 16 + l15;
#pragma unroll
      for (int ks = 0; ks < 2; ++ks)
        bfr[n4][ks] = *(const bf16x8*)(Bc + row * 64 + (((ks * 4 + lg) ^ swz) << 3));
    }
    __builtin_amdgcn_s_setprio(1);
#pragma unroll
    for (int m4 = 0; m4 < 4; ++m4)
#pragma unroll
      for (int n4 = 0; n4 < 4; ++n4)
#pragma unroll
        for (int ks = 0; ks < 2; ++ks)
          acc[m4][n4] = __builtin_amdgcn_mfma_f32_16x16x32_bf16(af[m4][ks], bfr[n4][ks], acc[m4][n4], 0, 0, 0);
    __builtin_amdgcn_s_setprio(0);

    asm volatile("" ::: "memory");
    __builtin_amdgcn_s_barrier();
    asm volatile("" ::: "memory");
  }
#undef STG1

#pragma unroll
  for (int m4 = 0; m4 < 4; ++m4) {
    const int rowb = m0 + wr * 64 + m4 * 16 + lg * 4;
#pragma unroll
    for (int n4 = 0; n4 < 4; ++n4) {
      const int col = n0 + wc * 64 + n4 * 16 + l15;
#pragma unroll
      for (int r4 = 0; r4 < 4; ++r4)
        outf[(size_t)(rowb + r4) * DMODEL + col] = acc[m4][n4][r4];
    }
  }
}

// ---------------- sliding-window flash attention (proven config: single-buffer, 4/CU) ----
// grid: (S/128, H, B), block 512 (8 waves), wave owns 16 q-rows.
// Fixed-shift softmax (p = exp(s - 12)); register-prefetched K/V staging one tile ahead.
// Balance flip: bz==1 reverses bx so co-resident blocks pair light+heavy q-tiles.
__global__ __launch_bounds__(512, 4) void attn_kernel(
    const short* __restrict__ qbuf,
    const short* __restrict__ kcache, const short* __restrict__ vcache,
    const int* __restrict__ block_tables, const int* __restrict__ context_lens,
    const int* __restrict__ window_size,
    short* __restrict__ attn_out)
{
  __shared__ short Ks[KT * 64];        // XOR-swizzled rows (row stride 128B)
  __shared__ short Vt[HDIM * VP];      // V^T, key-rotated within rows, stride 72
  __shared__ short Pb[8 * 16 * VP];    // per-wave P tiles, stride 72

  const int b = blockIdx.z, h = blockIdx.y;
  const int bx = (b & 1) ? ((int)gridDim.x - 1 - (int)blockIdx.x) : (int)blockIdx.x;
  const int q0 = bx * 128;
  const int ctx = context_lens[b];
  const int ws  = window_size[0];
  const int* bt = block_tables + b * NBLK;

  const int tid  = threadIdx.x;
  const int wave = tid >> 6, lane = tid & 63;
  const int l15 = lane & 15, lg = lane >> 4;
  const int qw = q0 + wave * 16;       // this wave's 16 q-rows

  const short* qp = qbuf + ((size_t)(b * S_LEN + qw + l15)) * DMODEL + h * HDIM;
  const bf16x8 qf0 = *(const bf16x8*)(qp + lg * 8);
  const bf16x8 qf1 = *(const bf16x8*)(qp + 32 + lg * 8);

  f32x4 oacc[4];
  float lrow[4];
#pragma unroll
  for (int i = 0; i < 4; i++) { oacc[i] = (f32x4)0.f; lrow[i] = 0.f; }

  int kstart = q0 - ws + 1; if (kstart < 0) kstart = 0; kstart &= ~(KT - 1);
  int kend = q0 + 128; if (kend > ctx) kend = ctx;

  const int kr = tid >> 3;             // staging: tile-local key 0..63
  const int dc = (tid & 7) << 3;       // staging: d-chunk
  const float rscale = 0.125f;         // HD^-0.5
  const float FM = 12.f;               // fixed softmax shift
  short* pw = Pb + wave * (16 * VP);
  const int swz = (l15 & 7) << 4;

  bf16x8 kreg = (bf16x8)0, vreg = (bf16x8)0;
  {
    const int key = kstart + kr;
    if (key < ctx) {
      const int slot = bt[key >> 4] * 16 + (key & 15);
      kreg = *(const bf16x8*)(kcache + (size_t)slot * DMODEL + h * HDIM + dc);
      vreg = *(const bf16x8*)(vcache + (size_t)slot * DMODEL + h * HDIM + dc);
    }
  }

  for (int kt = kstart; kt < kend; kt += KT) {
    __syncthreads();
    *(bf16x8*)((char*)Ks + kr * 128 + ((dc * 2) ^ ((kr & 7) << 4))) = kreg;
    const int vcol = (kr + dc) & 63;
#pragma unroll
    for (int j = 0; j < 8; j++) Vt[(dc + j) * VP + vcol] = vreg[j];
    kreg = (bf16x8)0; vreg = (bf16x8)0;
    if (kt + KT < kend) {
      const int key = kt + KT + kr;
      if (key < ctx) {
        const int slot = bt[key >> 4] * 16 + (key & 15);
        kreg = *(const bf16x8*)(kcache + (size_t)slot * DMODEL + h * HDIM + dc);
        vreg = *(const bf16x8*)(vcache + (size_t)slot * DMODEL + h * HDIM + dc);
      }
    }
    __syncthreads();

    if ((kt > qw + 15) || (kt + (KT - 1) <= qw - ws)) continue;

    f32x4 sacc[4];
#pragma unroll
    for (int cg = 0; cg < 4; cg++) sacc[cg] = (f32x4)0.f;
#pragma unroll
    for (int cg = 0; cg < 4; cg++) {
      const char* kp = (const char*)Ks + (cg * 16 + l15) * 128;
      const bf16x8 k0 = *(const bf16x8*)(kp + ((lg * 16) ^ swz));
      const bf16x8 k1 = *(const bf16x8*)(kp + ((64 + lg * 16) ^ swz));
      sacc[cg] = __builtin_amdgcn_mfma_f32_16x16x32_bf16(qf0, k0, sacc[cg], 0, 0, 0);
      sacc[cg] = __builtin_amdgcn_mfma_f32_16x16x32_bf16(qf1, k1, sacc[cg], 0, 0, 0);
    }

    const bool fullvis = (kt + (KT - 1) <= qw) && (qw + 15 - kt < ws) && (kt + (KT - 1) < ctx);

    if (fullvis) {
#pragma unroll
      for (int r = 0; r < 4; r++) {
        const float e0 = __expf(sacc[0][r] * rscale - FM);
        const float e1 = __expf(sacc[1][r] * rscale - FM);
        const float e2 = __expf(sacc[2][r] * rscale - FM);
        const float e3 = __expf(sacc[3][r] * rscale - FM);
        lrow[r] += (e0 + e1) + (e2 + e3);
        short* pr = pw + (lg * 4 + r) * VP + l15;
        pr[0]  = f2bf(e0); pr[16] = f2bf(e1);
        pr[32] = f2bf(e2); pr[48] = f2bf(e3);
      }
    } else {
#pragma unroll
      for (int r = 0; r < 4; r++) {
        const int qrow = qw + lg * 4 + r;
        const int key0 = kt + l15;
        const bool ok0 = (key0      <= qrow) && (qrow - key0      < ws) && (key0      < ctx);
        const bool ok1 = (key0 + 16 <= qrow) && (qrow - key0 - 16 < ws) && (key0 + 16 < ctx);
        const bool ok2 = (key0 + 32 <= qrow) && (qrow - key0 - 32 < ws) && (key0 + 32 < ctx);
        const bool ok3 = (key0 + 48 <= qrow) && (qrow - key0 - 48 < ws) && (key0 + 48 < ctx);
        const float e0 = ok0 ? __expf(sacc[0][r] * rscale - FM) : 0.f;
        const float e1 = ok1 ? __expf(sacc[1][r] * rscale - FM) : 0.f;
        const float e2 = ok2 ? __expf(sacc[2][r] * rscale - FM) : 0.f;
        const float e3 = ok3 ? __expf(sacc[3][r] * rscale - FM) : 0.f;
        lrow[r] += (e0 + e1) + (e2 + e3);
        short* pr = pw + (lg * 4 + r) * VP + l15;
        pr[0]  = f2bf(e0); pr[16] = f2bf(e1);
        pr[32] = f2bf(e2); pr[48] = f2bf(e3);
      }
    }

    asm volatile("s_waitcnt lgkmcnt(0)" ::: "memory");

#pragma unroll
    for (int kk = 0; kk < 2; kk++) {
      const bf16x8 pa = *(const bf16x8*)(pw + l15 * VP + kk * 32 + lg * 8);
#pragma unroll
      for (int dn = 0; dn < 4; dn++) {
        const int vrow = dn * 16 + l15;
        const int roff = (kk * 32 + lg * 8 + (vrow & ~7)) & 63;
        const bf16x8 vb = *(const bf16x8*)(Vt + vrow * VP + roff);
        oacc[dn] = __builtin_amdgcn_mfma_f32_16x16x32_bf16(pa, vb, oacc[dn], 0, 0, 0);
      }
    }
  }

#pragma unroll
  for (int r = 0; r < 4; r++) {
    float ls = lrow[r];
    ls += __shfl_xor(ls, 1); ls += __shfl_xor(ls, 2);
    ls += __shfl_xor(ls, 4); ls += __shfl_xor(ls, 8);
    const float inv = 1.f / fmaxf(ls, 1e-30f);
    const int row = qw + lg * 4 + r;
    short* op = attn_out + ((size_t)(b * S_LEN + row)) * DMODEL + h * HDIM;
#pragma unroll
    for (int dn = 0; dn < 4; dn++)
      op[dn * 16 + l15] = f2bf(oacc[dn][r] * inv);
  }
}

// ---------------- launch ----------------
extern "C" void kernel_launch(void* const* d_in, const int* in_sizes, int n_in,
                              void* d_out, int out_size, void* d_ws, size_t ws_size,
                              hipStream_t stream) {
  const float* x  = (const float*)d_in[0];
  const float* wq = (const float*)d_in[1];
  const float* wk = (const float*)d_in[2];
  const float* wv = (const float*)d_in[3];
  const float* wo = (const float*)d_in[4];
  const int* block_tables = (const int*)d_in[5];
  const int* slot_mapping = (const int*)d_in[6];
  const int* context_lens = (const int*)d_in[7];
  const int* window_size  = (const int*)d_in[8];
  float* out = (float*)d_out;

  char* ws = (char*)d_ws;
  short* xb     = (short*)(ws + (size_t)( 0 << 20));
  short* wqb    = (short*)(ws + (size_t)( 8 << 20));
  short* wkb    = (short*)(ws + (size_t)(10 << 20));
  short* wvb    = (short*)(ws + (size_t)(12 << 20));
  short* wob    = (short*)(ws + (size_t)(14 << 20));
  short* qbuf   = (short*)(ws + (size_t)(16 << 20));
  short* kcache = (short*)(ws + (size_t)(24 << 20));
  short* vcache = (short*)(ws + (size_t)(32 << 20));
  short* abuf   = (short*)(ws + (size_t)(40 << 20));

  // one-time: allow dynamic LDS (host state calls, not stream-captured)
  static bool ginit = [] {
    hipFuncSetAttribute(reinterpret_cast<const void*>(&gemm8_kernel),
                        hipFuncAttributeMaxDynamicSharedMemorySize, 131072);
    hipFuncSetAttribute(reinterpret_cast<const void*>(&gemm1_kernel),
                        hipFuncAttributeMaxDynamicSharedMemorySize, 65536);
    return true;
  }();
  (void)ginit;

  cvt_all_kernel<<<4096, 256, 0, stream>>>(x, wq, wk, wv, wo, xb, wqb, wkb, wvb, wob);

  gemm8_kernel<<<dim3(16, 12), 512, 131072, stream>>>(xb, wqb, wkb, wvb, slot_mapping,
                                                      qbuf, kcache, vcache);

  attn_kernel<<<dim3(S_LEN / 128, NHEAD, BATCH), 512, 0, stream>>>(
      qbuf, kcache, vcache, block_tables, context_lens, window_size, abuf);

  gemm1_kernel<<<dim3(32, 8), 256, 65536, stream>>>(abuf, wob, out);
}